// Round 1
// baseline (411.053 us; speedup 1.0000x reference)
//
#include <hip/hip_runtime.h>
#include <stdint.h>
#include <cmath>

// Problem: 4096x4096x3 f32 image -> grayscale -> 3x3 gaussian (reflect pad)
// -> exact 98.7% quantile threshold -> binary mask -> 5x5 opening -> int32 out.
//
// Quantile: q=0.987 in f32 gives pos = fl(fl(0.987)*16777215.0f) = 16559111.0
// exactly, so threshold == sorted_blur[16559111] (no interpolation).
// Exact selection via 2-level radix on u = floor(blur * 2^28).

#define HH 4096
#define WW 4096
#define NPIX 16777216u
#define KRANK 16559111u
#define TW 128
#define TH 32

__device__ __forceinline__ unsigned ukey(float v) {
  // v in [0,1): multiply by 2^28 is exact (exponent shift); trunc == floor.
  return (unsigned)(v * 268435456.0f);
}

// ---------------- K1: gray + separable 3x3 gaussian + level-1 histogram ----
__global__ __launch_bounds__(256) void k_blur_hist(const float* __restrict__ img,
    float* __restrict__ blur, unsigned* __restrict__ hist1,
    float kn0, float kn1) {
  __shared__ float g[TH + 2][TW + 2];
  __shared__ float hb[TH + 2][TW];
  __shared__ unsigned hist[4096];
  const int tid = threadIdx.x;
  for (int i = tid; i < 4096; i += 256) hist[i] = 0u;

  const int bx = blockIdx.x & 31;   // 4096/128 = 32 tiles across
  const int by = blockIdx.x >> 5;   // 4096/32 = 128 tiles down
  const int c0 = bx * TW, r0 = by * TH;
  const float* __restrict__ Rp = img;
  const float* __restrict__ Gp = img + (size_t)NPIX;
  const float* __restrict__ Bp = img + 2 * (size_t)NPIX;

  // load gray tile with 1-px halo, reflect padding (index -1 -> 1, H -> H-2)
  for (int idx = tid; idx < (TH + 2) * (TW + 2); idx += 256) {
    int row = idx / (TW + 2), col = idx - row * (TW + 2);
    int gr = r0 - 1 + row, gc = c0 - 1 + col;
    gr = (gr < 0) ? -gr : ((gr > HH - 1) ? (2 * (HH - 1) - gr) : gr);
    gc = (gc < 0) ? -gc : ((gc > WW - 1) ? (2 * (WW - 1) - gc) : gc);
    size_t o = (size_t)gr * WW + gc;
    // strict (non-fused) mul/add in the reference's association order
    float gray = __fadd_rn(__fadd_rn(__fmul_rn(0.2989f, Rp[o]),
                                     __fmul_rn(0.587f, Gp[o])),
                           __fmul_rn(0.114f, Bp[o]));
    g[row][col] = gray;
  }
  __syncthreads();

  // horizontal pass
  for (int idx = tid; idx < (TH + 2) * TW; idx += 256) {
    int row = idx / TW, col = idx - row * TW;
    hb[row][col] = __fadd_rn(__fadd_rn(__fmul_rn(kn0, g[row][col]),
                                       __fmul_rn(kn1, g[row][col + 1])),
                             __fmul_rn(kn0, g[row][col + 2]));
  }
  __syncthreads();

  // vertical pass + store + histogram of top 12 bits of u
  for (int idx = tid; idx < TH * TW; idx += 256) {
    int row = idx / TW, col = idx - row * TW;
    float v = __fadd_rn(__fadd_rn(__fmul_rn(kn0, hb[row][col]),
                                  __fmul_rn(kn1, hb[row + 1][col])),
                        __fmul_rn(kn0, hb[row + 2][col]));
    blur[(size_t)(r0 + row) * WW + (c0 + col)] = v;
    atomicAdd(&hist[ukey(v) >> 16], 1u);
  }
  __syncthreads();
  for (int i = tid; i < 4096; i += 256) {
    unsigned c = hist[i];
    if (c) atomicAdd(&hist1[i], c);
  }
}

// ---------------- K2: select level-1 bin containing rank KRANK -------------
__global__ __launch_bounds__(256) void k_sel1(const unsigned* __restrict__ hist1,
                                              unsigned* __restrict__ sel) {
  __shared__ unsigned part[256];
  const int t = threadIdx.x;
  unsigned loc[16];
  unsigned s = 0;
  for (int i = 0; i < 16; ++i) { loc[i] = hist1[t * 16 + i]; s += loc[i]; }
  part[t] = s;
  __syncthreads();
  for (int off = 1; off < 256; off <<= 1) {
    unsigned v = (t >= off) ? part[t - off] : 0u;
    __syncthreads();
    part[t] += v;
    __syncthreads();
  }
  unsigned incl = part[t], excl = incl - s;
  if (excl <= KRANK && KRANK < incl) {
    unsigned p = excl;
    for (int i = 0; i < 16; ++i) {
      if (KRANK < p + loc[i]) { sel[0] = (unsigned)(t * 16 + i); sel[1] = KRANK - p; break; }
      p += loc[i];
    }
  }
}

// ---------------- K3: level-2 histogram (only elements in selected bin) ----
__global__ __launch_bounds__(256) void k_hist2(const float4* __restrict__ blur4,
    const unsigned* __restrict__ sel, unsigned* __restrict__ hist2) {
  const unsigned b1 = sel[0];
  size_t i = (size_t)blockIdx.x * 256 + threadIdx.x;
  float4 v = blur4[i];
  unsigned u;
  u = ukey(v.x); if ((u >> 16) == b1) atomicAdd(&hist2[u & 0xFFFFu], 1u);
  u = ukey(v.y); if ((u >> 16) == b1) atomicAdd(&hist2[u & 0xFFFFu], 1u);
  u = ukey(v.z); if ((u >> 16) == b1) atomicAdd(&hist2[u & 0xFFFFu], 1u);
  u = ukey(v.w); if ((u >> 16) == b1) atomicAdd(&hist2[u & 0xFFFFu], 1u);
}

// ---------------- K4: select exact threshold value -------------------------
__global__ __launch_bounds__(1024) void k_sel2(const unsigned* __restrict__ hist2,
    const unsigned* __restrict__ sel, float* __restrict__ tptr) {
  __shared__ unsigned part[1024];
  const int t = threadIdx.x;
  const unsigned base = (unsigned)t * 64u;
  unsigned s = 0;
  for (int i = 0; i < 64; ++i) s += hist2[base + i];
  part[t] = s;
  __syncthreads();
  for (int off = 1; off < 1024; off <<= 1) {
    unsigned v = (t >= off) ? part[t - off] : 0u;
    __syncthreads();
    part[t] += v;
    __syncthreads();
  }
  unsigned incl = part[t], excl = incl - s;
  unsigned b1 = sel[0], r1 = sel[1];
  if (excl <= r1 && r1 < incl) {
    unsigned p = excl;
    for (int i = 0; i < 64; ++i) {
      unsigned c = hist2[base + i];
      if (r1 < p + c) {
        unsigned long long ustar = ((unsigned long long)b1 << 16) | (base + i);
        // exact f32 recovery: v_k = ustar * 2^-28 (bijective for v >= 2^-4)
        double vv = (double)ustar * (1.0 / 268435456.0);
        *tptr = (float)vv;
        break;
      }
      p += c;
    }
  }
}

// ---------------- K5: mask = blur >= T, bit-packed via ballot --------------
__global__ __launch_bounds__(256) void k_mask(const float* __restrict__ blur,
    const float* __restrict__ tptr, unsigned long long* __restrict__ mbits) {
  size_t i = (size_t)blockIdx.x * 256 + threadIdx.x;
  float T = *tptr;
  unsigned long long w = __ballot(blur[i] >= T);
  if ((threadIdx.x & 63) == 0) mbits[i >> 6] = w;
}

// ---------------- K6: 5x5 erosion (zero border) on bit-packed mask ---------
__global__ __launch_bounds__(256) void k_erode(
    const unsigned long long* __restrict__ mbits,
    unsigned long long* __restrict__ ebits) {
  int w = blockIdx.x * 256 + threadIdx.x;   // word id, 4096 rows x 64 words
  int r = w >> 6, wc = w & 63;
  unsigned long long acc = ~0ull;
  for (int dr = -2; dr <= 2; ++dr) {
    int rr = r + dr;
    unsigned long long h = 0ull;
    if (rr >= 0 && rr <= HH - 1) {
      int rb = (rr << 6) + wc;
      unsigned long long C = mbits[rb];
      unsigned long long L = (wc > 0) ? mbits[rb - 1] : 0ull;
      unsigned long long R = (wc < 63) ? mbits[rb + 1] : 0ull;
      h = C & ((C >> 1) | (R << 63)) & ((C >> 2) | (R << 62))
            & ((C << 1) | (L >> 63)) & ((C << 2) | (L >> 62));
    }
    acc &= h;
  }
  ebits[w] = acc;
}

// ---------------- K7: 5x5 dilation + expand to int32 -----------------------
__global__ __launch_bounds__(256) void k_dilate_out(
    const unsigned long long* __restrict__ ebits, int* __restrict__ out) {
  __shared__ unsigned long long wbuf[256];
  int w = blockIdx.x * 256 + threadIdx.x;
  int r = w >> 6, wc = w & 63;
  unsigned long long acc = 0ull;
  for (int dr = -2; dr <= 2; ++dr) {
    int rr = r + dr;
    if (rr < 0 || rr > HH - 1) continue;
    int rb = (rr << 6) + wc;
    unsigned long long C = ebits[rb];
    unsigned long long L = (wc > 0) ? ebits[rb - 1] : 0ull;
    unsigned long long R = (wc < 63) ? ebits[rb + 1] : 0ull;
    acc |= C | ((C >> 1) | (R << 63)) | ((C >> 2) | (R << 62))
             | ((C << 1) | (L >> 63)) | ((C << 2) | (L >> 62));
  }
  wbuf[threadIdx.x] = acc;
  __syncthreads();
  size_t p0 = (size_t)blockIdx.x * 16384;
  for (int j = threadIdx.x; j < 16384; j += 256)
    out[p0 + j] = (int)((wbuf[j >> 6] >> (j & 63)) & 1ull);
}

// ---------------------------------------------------------------------------
extern "C" void kernel_launch(void* const* d_in, const int* in_sizes, int n_in,
                              void* d_out, int out_size, void* d_ws, size_t ws_size,
                              hipStream_t stream) {
  (void)in_sizes; (void)n_in; (void)out_size; (void)ws_size;
  const float* img = (const float*)d_in[0];
  int* out = (int*)d_out;
  char* ws = (char*)d_ws;

  // ws layout (total ~68.3 MB):
  float* blur = (float*)ws;                                    // 64 MB
  unsigned* hist1 = (unsigned*)(ws + 67108864);                // 16 KB
  unsigned* hist2 = (unsigned*)(ws + 67108864 + 16384);        // 256 KB
  unsigned* sel   = (unsigned*)(ws + 67108864 + 16384 + 262144);       // 8 B (pad 256)
  float* tptr     = (float*)(ws + 67108864 + 16384 + 262144 + 256);    // 4 B (pad 256)
  unsigned long long* mbits =
      (unsigned long long*)(ws + 67108864 + 16384 + 262144 + 512);     // 2 MB
  unsigned long long* ebits = mbits + 262144;                          // 2 MB

  // Gaussian weights in f32 exactly as jnp would constant-fold:
  // x/0.8f -> +-1.25f exactly; arg = -0.78125f exactly; only expf rounds.
  float t = 1.0f / 0.8f;
  float k0 = expf(-0.5f * (t * t));
  float k1 = 1.0f;                 // expf(0)
  float s = (k0 + k1) + k0;        // jnp sum fold order
  float kn0 = k0 / s, kn1 = k1 / s;

  hipMemsetAsync(hist1, 0, 16384 + 262144, stream);  // hist1+hist2 contiguous
  k_blur_hist<<<4096, 256, 0, stream>>>(img, blur, hist1, kn0, kn1);
  k_sel1<<<1, 256, 0, stream>>>(hist1, sel);
  k_hist2<<<16384, 256, 0, stream>>>((const float4*)blur, sel, hist2);
  k_sel2<<<1, 1024, 0, stream>>>(hist2, sel, tptr);
  k_mask<<<65536, 256, 0, stream>>>(blur, tptr, mbits);
  k_erode<<<1024, 256, 0, stream>>>(mbits, ebits);
  k_dilate_out<<<1024, 256, 0, stream>>>(ebits, out);
}

// Round 2
// 371.469 us; speedup vs baseline: 1.1066x; 1.1066x over previous
//
#include <hip/hip_runtime.h>
#include <stdint.h>
#include <cmath>

// 4096x4096x3 f32 -> gray -> 3x3 gaussian (reflect) -> exact 98.7% quantile
// threshold -> mask -> 5x5 binary opening -> int32.
//
// Quantile: pos = fl(fl(0.987)*16777215.0f) = 16559111.0 exactly, so the
// threshold is exactly order statistic #16559111. Selection via 2-level radix
// on u = floor(blur * 2^28) (exact: *2^28 is an exponent shift for v in [0,1)).
// mask = (blur >= T) <=> (u >= ustar), all integer-exact (round 1: absmax 0).

#define HH 4096
#define WW 4096
#define KRANK 16559111u
#define CAP 65536u

__device__ __forceinline__ unsigned ukey(float v) {
  return (unsigned)(v * 268435456.0f);
}
__device__ __forceinline__ int refl(int i) {
  return i < 0 ? -i : (i > 4095 ? 8190 - i : i);
}
__device__ __forceinline__ float grayf(float r, float g, float b) {
  return __fadd_rn(__fadd_rn(__fmul_rn(0.2989f, r), __fmul_rn(0.587f, g)),
                   __fmul_rn(0.114f, b));
}
__device__ __forceinline__ float tap3(float a, float b, float c, float kn0, float kn1) {
  return __fadd_rn(__fadd_rn(__fmul_rn(kn0, a), __fmul_rn(kn1, b)),
                   __fmul_rn(kn0, c));
}

// ---------------- K1: gray + separable blur (register-rolling) + hist1 -----
// Block = 256 thr = 4 waves. Wave: 256 cols x 16 rows, lane owns 4 cols.
// Grid: 16 col-tiles x 64 row-tiles = 1024 blocks.
__global__ __launch_bounds__(256) void k_blur(const float* __restrict__ img,
    float4* __restrict__ blur4, unsigned* __restrict__ hist1,
    float kn0, float kn1) {
  __shared__ unsigned hist[4096];
  const int tid = threadIdx.x;
  for (int i = tid; i < 4096; i += 256) hist[i] = 0u;
  __syncthreads();

  const int lane = tid & 63, wv = tid >> 6;
  const int bc = (blockIdx.x & 15) << 8;        // column base of block
  const int r0 = (blockIdx.x >> 4) << 6;        // row base of block
  const int rstart = r0 + (wv << 4);            // this wave's first out row
  const float* __restrict__ Rp = img;
  const float* __restrict__ Gp = img + 16777216;
  const float* __restrict__ Bp = img + 33554432;
  const int c4 = bc + (lane << 2);

  auto hrow = [&](int r) -> float4 {
    const int gr = refl(r);
    const size_t base = ((size_t)gr << 12) + c4;
    float4 R = *(const float4*)(Rp + base);
    float4 G = *(const float4*)(Gp + base);
    float4 B = *(const float4*)(Bp + base);
    float4 g;
    g.x = grayf(R.x, G.x, B.x);
    g.y = grayf(R.y, G.y, B.y);
    g.z = grayf(R.z, G.z, B.z);
    g.w = grayf(R.w, G.w, B.w);
    float gl = __shfl_up(g.w, 1);    // col c4-1 from lane-1
    float gr_ = __shfl_down(g.x, 1); // col c4+4 from lane+1
    if (lane == 0) {
      if (bc == 0) gl = g.y;         // reflect(-1) = 1
      else {
        size_t o = ((size_t)gr << 12) + bc - 1;
        gl = grayf(Rp[o], Gp[o], Bp[o]);
      }
    }
    if (lane == 63) {
      if (bc == 3840) gr_ = g.z;     // reflect(4096) = 4094
      else {
        size_t o = ((size_t)gr << 12) + bc + 256;
        gr_ = grayf(Rp[o], Gp[o], Bp[o]);
      }
    }
    float4 h;
    h.x = tap3(gl, g.x, g.y, kn0, kn1);
    h.y = tap3(g.x, g.y, g.z, kn0, kn1);
    h.z = tap3(g.y, g.z, g.w, kn0, kn1);
    h.w = tap3(g.z, g.w, gr_, kn0, kn1);
    return h;
  };

  float4 h0 = hrow(rstart - 1);
  float4 h1 = hrow(rstart);
  for (int i = 0; i < 16; ++i) {
    float4 h2 = hrow(rstart + 1 + i);
    float4 v;
    v.x = tap3(h0.x, h1.x, h2.x, kn0, kn1);
    v.y = tap3(h0.y, h1.y, h2.y, kn0, kn1);
    v.z = tap3(h0.z, h1.z, h2.z, kn0, kn1);
    v.w = tap3(h0.w, h1.w, h2.w, kn0, kn1);
    blur4[(((size_t)(rstart + i) << 12) + c4) >> 2] = v;
    atomicAdd(&hist[ukey(v.x) >> 16], 1u);
    atomicAdd(&hist[ukey(v.y) >> 16], 1u);
    atomicAdd(&hist[ukey(v.z) >> 16], 1u);
    atomicAdd(&hist[ukey(v.w) >> 16], 1u);
    h0 = h1; h1 = h2;
  }
  __syncthreads();
  for (int i = tid; i < 4096; i += 256) {
    unsigned c = hist[i];
    if (c) atomicAdd(&hist1[i], c);
  }
}

// ---------------- K2: select level-1 bin containing rank KRANK -------------
__global__ __launch_bounds__(256) void k_sel1(const unsigned* __restrict__ hist1,
                                              unsigned* __restrict__ sel) {
  __shared__ unsigned part[256];
  const int t = threadIdx.x;
  unsigned loc[16];
  unsigned s = 0;
  for (int i = 0; i < 16; ++i) { loc[i] = hist1[t * 16 + i]; s += loc[i]; }
  part[t] = s;
  __syncthreads();
  for (int off = 1; off < 256; off <<= 1) {
    unsigned v = (t >= off) ? part[t - off] : 0u;
    __syncthreads();
    part[t] += v;
    __syncthreads();
  }
  unsigned incl = part[t], excl = incl - s;
  if (excl <= KRANK && KRANK < incl) {
    unsigned p = excl;
    for (int i = 0; i < 16; ++i) {
      if (KRANK < p + loc[i]) { sel[0] = (unsigned)(t * 16 + i); sel[1] = KRANK - p; break; }
      p += loc[i];
    }
  }
}

// ---------------- K3: fused mask(definite bits) + hist2 + in-bin list ------
__global__ __launch_bounds__(256) void k_pass2(const float* __restrict__ blur,
    const unsigned* __restrict__ sel, unsigned* __restrict__ hist2,
    unsigned* __restrict__ cnt, unsigned long long* __restrict__ list,
    unsigned long long* __restrict__ mbits) {
  const unsigned b1 = sel[0];
  const unsigned ub = (b1 + 1u) << 16;   // b1==4095 -> 2^28, still > all u
  unsigned i = blockIdx.x * 256 + threadIdx.x;
  unsigned u = ukey(blur[i]);
  unsigned long long w = __ballot(u >= ub);
  if ((threadIdx.x & 63) == 0) mbits[i >> 6] = w;
  if ((u >> 16) == b1) {
    atomicAdd(&hist2[u & 0xFFFFu], 1u);
    unsigned idx = atomicAdd(cnt, 1u);
    if (idx < CAP) list[idx] = ((unsigned long long)i << 16) | (u & 0xFFFFu);
  }
}

// ---------------- K4: select low-16 of the rank-KRANK key ------------------
__global__ __launch_bounds__(1024) void k_sel2(const unsigned* __restrict__ hist2,
                                               unsigned* __restrict__ sel) {
  __shared__ unsigned part[1024];
  const int t = threadIdx.x;
  const unsigned base = (unsigned)t * 64u;
  unsigned s = 0;
  for (int i = 0; i < 64; ++i) s += hist2[base + i];
  part[t] = s;
  __syncthreads();
  for (int off = 1; off < 1024; off <<= 1) {
    unsigned v = (t >= off) ? part[t - off] : 0u;
    __syncthreads();
    part[t] += v;
    __syncthreads();
  }
  unsigned incl = part[t], excl = incl - s;
  unsigned r1 = sel[1];
  if (excl <= r1 && r1 < incl) {
    unsigned p = excl;
    for (int i = 0; i < 64; ++i) {
      unsigned c = hist2[base + i];
      if (r1 < p + c) { sel[2] = base + i; break; }
      p += c;
    }
  }
}

// ---------------- K5: set bits for in-bin pixels with low16 >= lo* ---------
__global__ __launch_bounds__(256) void k_fixup(
    const unsigned long long* __restrict__ list, const unsigned* __restrict__ cnt,
    const unsigned* __restrict__ sel, unsigned long long* __restrict__ mbits) {
  unsigned n = *cnt; if (n > CAP) n = CAP;
  const unsigned lo = sel[2];
  for (unsigned j = blockIdx.x * 256 + threadIdx.x; j < n; j += 256 * gridDim.x) {
    unsigned long long e = list[j];
    if ((unsigned)(e & 0xFFFFu) >= lo) {
      unsigned long long pix = e >> 16;
      atomicOr(&mbits[pix >> 6], 1ull << (pix & 63));
    }
  }
}

// ---------------- K6: 5x5 erosion (zero border) on bit-packed mask ---------
__global__ __launch_bounds__(256) void k_erode(
    const unsigned long long* __restrict__ mbits,
    unsigned long long* __restrict__ ebits) {
  int w = blockIdx.x * 256 + threadIdx.x;
  int r = w >> 6, wc = w & 63;
  unsigned long long acc = ~0ull;
  for (int dr = -2; dr <= 2; ++dr) {
    int rr = r + dr;
    unsigned long long h = 0ull;
    if (rr >= 0 && rr <= HH - 1) {
      int rb = (rr << 6) + wc;
      unsigned long long C = mbits[rb];
      unsigned long long L = (wc > 0) ? mbits[rb - 1] : 0ull;
      unsigned long long R = (wc < 63) ? mbits[rb + 1] : 0ull;
      h = C & ((C >> 1) | (R << 63)) & ((C >> 2) | (R << 62))
            & ((C << 1) | (L >> 63)) & ((C << 2) | (L >> 62));
    }
    acc &= h;
  }
  ebits[w] = acc;
}

// ---------------- K7: 5x5 dilation + expand to int32 (int4 stores) ---------
__global__ __launch_bounds__(256) void k_dilate_out(
    const unsigned long long* __restrict__ ebits, int4* __restrict__ out4) {
  __shared__ unsigned long long wbuf[256];
  int w = blockIdx.x * 256 + threadIdx.x;
  int r = w >> 6, wc = w & 63;
  unsigned long long acc = 0ull;
  for (int dr = -2; dr <= 2; ++dr) {
    int rr = r + dr;
    if (rr < 0 || rr > HH - 1) continue;
    int rb = (rr << 6) + wc;
    unsigned long long C = ebits[rb];
    unsigned long long L = (wc > 0) ? ebits[rb - 1] : 0ull;
    unsigned long long R = (wc < 63) ? ebits[rb + 1] : 0ull;
    acc |= C | ((C >> 1) | (R << 63)) | ((C >> 2) | (R << 62))
             | ((C << 1) | (L >> 63)) | ((C << 2) | (L >> 62));
  }
  wbuf[threadIdx.x] = acc;
  __syncthreads();
  size_t p0 = (size_t)blockIdx.x * 4096;
  for (int j = threadIdx.x; j < 4096; j += 256) {
    unsigned long long word = wbuf[j >> 4];
    unsigned nib = (unsigned)(word >> ((j & 15) << 2)) & 0xFu;
    out4[p0 + j] = make_int4(nib & 1, (nib >> 1) & 1, (nib >> 2) & 1, (nib >> 3) & 1);
  }
}

// ---------------------------------------------------------------------------
extern "C" void kernel_launch(void* const* d_in, const int* in_sizes, int n_in,
                              void* d_out, int out_size, void* d_ws, size_t ws_size,
                              hipStream_t stream) {
  (void)in_sizes; (void)n_in; (void)out_size; (void)ws_size;
  const float* img = (const float*)d_in[0];
  char* ws = (char*)d_ws;

  // ws layout (~68.8 MB total; round 1 used 69.3 MB successfully):
  float* blur = (float*)ws;                                      // 64 MB
  unsigned* hist1 = (unsigned*)(ws + 67108864);                  // 16 KB
  unsigned* hist2 = (unsigned*)(ws + 67125248);                  // 256 KB
  unsigned* cnt   = (unsigned*)(ws + 67387392);                  // 64 B slot
  unsigned* sel   = (unsigned*)(ws + 67387456);                  // 64 B slot
  unsigned long long* list  = (unsigned long long*)(ws + 67387520);  // 512 KB
  unsigned long long* mbits = (unsigned long long*)(ws + 67911808);  // 2 MB
  unsigned long long* ebits = (unsigned long long*)(ws + 70008960);  // 2 MB

  // Gaussian weights as jnp constant-folds them (f32; only expf rounds):
  float t = 1.0f / 0.8f;
  float k0 = expf(-0.5f * (t * t));
  float k1 = 1.0f;
  float s = (k0 + k1) + k0;
  float kn0 = k0 / s, kn1 = k1 / s;

  // zero hist1 + hist2 + cnt (contiguous)
  hipMemsetAsync(hist1, 0, 16384 + 262144 + 64, stream);
  k_blur<<<1024, 256, 0, stream>>>(img, (float4*)blur, hist1, kn0, kn1);
  k_sel1<<<1, 256, 0, stream>>>(hist1, sel);
  k_pass2<<<65536, 256, 0, stream>>>(blur, sel, hist2, cnt, list, mbits);
  k_sel2<<<1, 1024, 0, stream>>>(hist2, sel);
  k_fixup<<<32, 256, 0, stream>>>(list, cnt, sel, mbits);
  k_erode<<<1024, 256, 0, stream>>>(mbits, ebits);
  k_dilate_out<<<1024, 256, 0, stream>>>(ebits, (int4*)d_out);
}

// Round 4
// 365.741 us; speedup vs baseline: 1.1239x; 1.0157x over previous
//
#include <hip/hip_runtime.h>
#include <stdint.h>
#include <cmath>

// 4096x4096x3 f32 -> gray -> 3x3 gaussian (reflect) -> exact 98.7% quantile
// threshold -> mask -> 5x5 binary opening -> int32.
//
// Quantile: pos = fl(fl(0.987)*16777215.0f) = 16559111.0 exactly, so the
// threshold is exactly order statistic #16559111. Selection via 2-level radix
// on u = floor(blur * 2^28) (exact for v in [0,1)); mask = (u >= ustar).
// Validated absmax=0 in rounds 1-2. (Round 3 was an infra failure; this is
// the same source resubmitted.)

#define HH 4096
#define WW 4096
#define KRANK 16559111u
#define CAP 65536u

__device__ __forceinline__ unsigned ukey(float v) {
  return (unsigned)(v * 268435456.0f);
}
__device__ __forceinline__ int refl(int i) {
  return i < 0 ? -i : (i > 4095 ? 8190 - i : i);
}
__device__ __forceinline__ float grayf(float r, float g, float b) {
  return __fadd_rn(__fadd_rn(__fmul_rn(0.2989f, r), __fmul_rn(0.587f, g)),
                   __fmul_rn(0.114f, b));
}
__device__ __forceinline__ float tap3(float a, float b, float c, float kn0, float kn1) {
  return __fadd_rn(__fadd_rn(__fmul_rn(kn0, a), __fmul_rn(kn1, b)),
                   __fmul_rn(kn0, c));
}

// ---------------- K1: gray + separable blur (branchless halo) + hist1 ------
// Block = 512 thr = 8 waves; wave owns 256 cols x 8 rows (lane = 4 cols).
// Grid = 16 col-tiles x 64 row-tiles (64 rows/block) = 1024 blocks.
__global__ __launch_bounds__(512) void k_blur(const float* __restrict__ img,
    float4* __restrict__ blur4, unsigned* __restrict__ hist1,
    float kn0, float kn1) {
  __shared__ unsigned hist[4096];
  const int tid = threadIdx.x;
  #pragma unroll
  for (int i = tid; i < 4096; i += 512) hist[i] = 0u;
  __syncthreads();

  const int lane = tid & 63, wv = tid >> 6;
  const int bc = (blockIdx.x & 15) << 8;        // column base of block
  const int r0 = (blockIdx.x >> 4) << 6;        // row base of block
  const int rstart = r0 + (wv << 3);            // wave's first output row
  const float* __restrict__ Rp = img;
  const float* __restrict__ Gp = img + 16777216;
  const float* __restrict__ Bp = img + 33554432;
  const int c4 = bc + (lane << 2);
  // lane-selected halo column (branchless): lane0 -> left, lane63 -> right
  const int colL = (bc == 0) ? 1 : bc - 1;            // reflect(-1)=1
  const int colR = (bc == 3840) ? 4094 : bc + 256;    // reflect(4096)=4094
  const int hc = (lane == 0) ? colL : ((lane == 63) ? colR : c4);

  auto hrow = [&](int r) -> float4 {
    const size_t base = ((size_t)refl(r) << 12);
    float4 R = *(const float4*)(Rp + base + c4);
    float4 G = *(const float4*)(Gp + base + c4);
    float4 B = *(const float4*)(Bp + base + c4);
    float hr = Rp[base + hc], hg = Gp[base + hc], hb = Bp[base + hc];
    float4 g;
    g.x = grayf(R.x, G.x, B.x);
    g.y = grayf(R.y, G.y, B.y);
    g.z = grayf(R.z, G.z, B.z);
    g.w = grayf(R.w, G.w, B.w);
    float ghalo = grayf(hr, hg, hb);
    float gl = __shfl_up(g.w, 1);
    float gr_ = __shfl_down(g.x, 1);
    gl = (lane == 0) ? ghalo : gl;
    gr_ = (lane == 63) ? ghalo : gr_;
    float4 h;
    h.x = tap3(gl, g.x, g.y, kn0, kn1);
    h.y = tap3(g.x, g.y, g.z, kn0, kn1);
    h.z = tap3(g.y, g.z, g.w, kn0, kn1);
    h.w = tap3(g.z, g.w, gr_, kn0, kn1);
    return h;
  };

  float4 h0 = hrow(rstart - 1);
  float4 h1 = hrow(rstart);
  #pragma unroll
  for (int i = 0; i < 8; ++i) {
    float4 h2 = hrow(rstart + 1 + i);
    float4 v;
    v.x = tap3(h0.x, h1.x, h2.x, kn0, kn1);
    v.y = tap3(h0.y, h1.y, h2.y, kn0, kn1);
    v.z = tap3(h0.z, h1.z, h2.z, kn0, kn1);
    v.w = tap3(h0.w, h1.w, h2.w, kn0, kn1);
    blur4[(((size_t)(rstart + i) << 12) + c4) >> 2] = v;
    atomicAdd(&hist[ukey(v.x) >> 16], 1u);
    atomicAdd(&hist[ukey(v.y) >> 16], 1u);
    atomicAdd(&hist[ukey(v.z) >> 16], 1u);
    atomicAdd(&hist[ukey(v.w) >> 16], 1u);
    h0 = h1; h1 = h2;
  }
  __syncthreads();
  #pragma unroll
  for (int i = tid; i < 4096; i += 512) {
    unsigned c = hist[i];
    if (c) atomicAdd(&hist1[i], c);
  }
}

// ---------------- K2: select level-1 bin containing rank KRANK -------------
__global__ __launch_bounds__(256) void k_sel1(const unsigned* __restrict__ hist1,
                                              unsigned* __restrict__ sel) {
  __shared__ unsigned part[256];
  const int t = threadIdx.x;
  unsigned loc[16];
  unsigned s = 0;
  for (int i = 0; i < 16; ++i) { loc[i] = hist1[t * 16 + i]; s += loc[i]; }
  part[t] = s;
  __syncthreads();
  for (int off = 1; off < 256; off <<= 1) {
    unsigned v = (t >= off) ? part[t - off] : 0u;
    __syncthreads();
    part[t] += v;
    __syncthreads();
  }
  unsigned incl = part[t], excl = incl - s;
  if (excl <= KRANK && KRANK < incl) {
    unsigned p = excl;
    for (int i = 0; i < 16; ++i) {
      if (KRANK < p + loc[i]) { sel[0] = (unsigned)(t * 16 + i); sel[1] = KRANK - p; break; }
      p += loc[i];
    }
  }
}

// ---------------- K3: fused mask bits + hist2 + block-aggregated list ------
// Grid 2048 blocks x 256 thr; block handles 8192 consecutive pixels (2 rows).
__global__ __launch_bounds__(256) void k_pass2(const float* __restrict__ blur,
    const unsigned* __restrict__ sel, unsigned* __restrict__ hist2,
    unsigned* __restrict__ cnt, unsigned long long* __restrict__ list,
    unsigned long long* __restrict__ mbits) {
  __shared__ unsigned lcnt, lbase;
  __shared__ unsigned lidx[256];
  __shared__ unsigned short lkey[256];
  if (threadIdx.x == 0) lcnt = 0u;
  __syncthreads();
  const unsigned b1 = sel[0];
  const unsigned ub = (b1 + 1u) << 16;
  const unsigned base = blockIdx.x * 8192u + threadIdx.x;
  #pragma unroll 4
  for (int it = 0; it < 32; ++it) {
    unsigned i = base + (unsigned)it * 256u;
    unsigned u = ukey(blur[i]);
    unsigned long long w = __ballot(u >= ub);
    if ((threadIdx.x & 63) == 0) mbits[i >> 6] = w;
    if ((u >> 16) == b1) {
      atomicAdd(&hist2[u & 0xFFFFu], 1u);
      unsigned x = atomicAdd(&lcnt, 1u);
      if (x < 256u) { lidx[x] = i; lkey[x] = (unsigned short)(u & 0xFFFFu); }
      else {                        // overflow fallback: direct global append
        unsigned g = atomicAdd(cnt, 1u);
        if (g < CAP) list[g] = ((unsigned long long)i << 16) | (u & 0xFFFFu);
      }
    }
  }
  __syncthreads();
  unsigned n = lcnt > 256u ? 256u : lcnt;
  if (threadIdx.x == 0 && n) lbase = atomicAdd(cnt, n);
  __syncthreads();
  if (threadIdx.x < n) {
    unsigned g = lbase + threadIdx.x;
    if (g < CAP)
      list[g] = ((unsigned long long)lidx[threadIdx.x] << 16) | (unsigned)lkey[threadIdx.x];
  }
}

// ---------------- K4: select low16 of rank key + fixup in-bin mask bits ----
__global__ __launch_bounds__(1024) void k_sel2fix(const unsigned* __restrict__ hist2,
    const unsigned* __restrict__ sel, const unsigned* __restrict__ cnt,
    const unsigned long long* __restrict__ list,
    unsigned long long* __restrict__ mbits) {
  __shared__ unsigned part[1024];
  __shared__ unsigned sLo;
  const int t = threadIdx.x;
  const unsigned base = (unsigned)t * 64u;
  unsigned s = 0;
  for (int i = 0; i < 64; ++i) s += hist2[base + i];
  part[t] = s;
  __syncthreads();
  for (int off = 1; off < 1024; off <<= 1) {
    unsigned v = (t >= off) ? part[t - off] : 0u;
    __syncthreads();
    part[t] += v;
    __syncthreads();
  }
  unsigned incl = part[t], excl = incl - s;
  const unsigned r1 = sel[1];
  if (excl <= r1 && r1 < incl) {
    unsigned p = excl;
    for (int i = 0; i < 64; ++i) {
      unsigned c = hist2[base + i];
      if (r1 < p + c) { sLo = base + i; break; }
      p += c;
    }
  }
  __syncthreads();
  const unsigned lo = sLo;
  unsigned n = *cnt; if (n > CAP) n = CAP;
  for (unsigned j = t; j < n; j += 1024) {
    unsigned long long e = list[j];
    if ((unsigned)(e & 0xFFFFu) >= lo) {
      unsigned long long pix = e >> 16;
      atomicOr(&mbits[pix >> 6], 1ull << (pix & 63));
    }
  }
}

// ---------------- K5: fused 5x5 erode (zero border) + dilate + int32 out ---
// Grid 512 blocks x 256 thr; block = 8 output rows.
__global__ __launch_bounds__(256) void k_morph(
    const unsigned long long* __restrict__ mbits, int4* __restrict__ out4) {
  __shared__ unsigned long long er[12][64];   // eroded rows r0-2 .. r0+9
  __shared__ unsigned long long dl[8][64];    // dilated rows r0 .. r0+7
  const int r0 = blockIdx.x << 3;
  for (int t = threadIdx.x; t < 12 * 64; t += 256) {
    int lr = t >> 6, wc = t & 63;
    int rr = r0 - 2 + lr;
    unsigned long long acc = 0ull;
    if (rr >= 0 && rr < HH) {
      acc = ~0ull;
      #pragma unroll
      for (int dr = -2; dr <= 2; ++dr) {
        int mr = rr + dr;
        unsigned long long h = 0ull;
        if (mr >= 0 && mr < HH) {
          int rb = (mr << 6) + wc;
          unsigned long long C = mbits[rb];
          unsigned long long L = (wc > 0) ? mbits[rb - 1] : 0ull;
          unsigned long long R = (wc < 63) ? mbits[rb + 1] : 0ull;
          h = C & ((C >> 1) | (R << 63)) & ((C >> 2) | (R << 62))
                & ((C << 1) | (L >> 63)) & ((C << 2) | (L >> 62));
        }
        acc &= h;
      }
    }
    er[lr][wc] = acc;
  }
  __syncthreads();
  for (int t = threadIdx.x; t < 8 * 64; t += 256) {
    int lr = t >> 6, wc = t & 63;
    unsigned long long acc = 0ull;
    #pragma unroll
    for (int dr = 0; dr <= 4; ++dr) {
      unsigned long long C = er[lr + dr][wc];
      unsigned long long L = (wc > 0) ? er[lr + dr][wc - 1] : 0ull;
      unsigned long long R = (wc < 63) ? er[lr + dr][wc + 1] : 0ull;
      acc |= C | ((C >> 1) | (R << 63)) | ((C >> 2) | (R << 62))
               | ((C << 1) | (L >> 63)) | ((C << 2) | (L >> 62));
    }
    dl[lr][wc] = acc;
  }
  __syncthreads();
  const size_t p0 = (size_t)r0 << 10;         // out4 index base (1024 per row)
  for (int j = threadIdx.x; j < 8192; j += 256) {
    unsigned long long word = dl[j >> 10][(j >> 4) & 63];
    unsigned nib = (unsigned)(word >> ((j & 15) << 2)) & 0xFu;
    out4[p0 + j] = make_int4(nib & 1, (nib >> 1) & 1, (nib >> 2) & 1, (nib >> 3) & 1);
  }
}

// ---------------------------------------------------------------------------
extern "C" void kernel_launch(void* const* d_in, const int* in_sizes, int n_in,
                              void* d_out, int out_size, void* d_ws, size_t ws_size,
                              hipStream_t stream) {
  (void)in_sizes; (void)n_in; (void)out_size; (void)ws_size;
  const float* img = (const float*)d_in[0];
  char* ws = (char*)d_ws;

  float* blur = (float*)ws;                                      // 64 MB
  unsigned* hist1 = (unsigned*)(ws + 67108864);                  // 16 KB
  unsigned* hist2 = (unsigned*)(ws + 67125248);                  // 256 KB
  unsigned* cnt   = (unsigned*)(ws + 67387392);                  // 64 B slot
  unsigned* sel   = (unsigned*)(ws + 67387456);                  // 64 B slot
  unsigned long long* list  = (unsigned long long*)(ws + 67387520);  // 512 KB
  unsigned long long* mbits = (unsigned long long*)(ws + 67911808);  // 2 MB

  // Gaussian weights as jnp constant-folds them (f32; only expf rounds):
  float t = 1.0f / 0.8f;
  float k0 = expf(-0.5f * (t * t));
  float k1 = 1.0f;
  float s = (k0 + k1) + k0;
  float kn0 = k0 / s, kn1 = k1 / s;

  hipMemsetAsync(hist1, 0, 16384 + 262144 + 64, stream);  // hist1+hist2+cnt
  k_blur<<<1024, 512, 0, stream>>>(img, (float4*)blur, hist1, kn0, kn1);
  k_sel1<<<1, 256, 0, stream>>>(hist1, sel);
  k_pass2<<<2048, 256, 0, stream>>>(blur, sel, hist2, cnt, list, mbits);
  k_sel2fix<<<1, 1024, 0, stream>>>(hist2, sel, cnt, list, mbits);
  k_morph<<<512, 256, 0, stream>>>(mbits, (int4*)d_out);
}